// Round 6
// baseline (370.451 us; speedup 1.0000x reference)
//
#include <hip/hip_runtime.h>
#include <stdint.h>

// ---------------------------------------------------------------------------
// Soft Decision Tree forward: DEPTH=10, INPUT_DIM=2048, OUTPUT_DIM=1000,
// NUM_INNER=1023, NUM_LEAF=1024, BATCH=8192.
// Outputs (flat concat): logits[8192*1000], mu[8192*1024], penalty[1],
// all_pp[8192*2047].
//
// R8: GEMM pipeline deepened (the one change vs R7, whose dbuf gave -24 us):
// 3 LDS buffers, stage-2-ahead, counted s_waitcnt vmcnt(4) + RAW s_barrier
// per K-subtile — loads stay in flight across barriers (T4); vmcnt reaches 0
// only in the epilogue. Buffer rotation via wave-uniform pointers.
// Pipeline: convert -> GEMM1(sigmoid) -> tree_expand -> transpose (R2) ->
// GEMM2 -> penalty_nodes.
// ---------------------------------------------------------------------------

typedef short bf16x8 __attribute__((ext_vector_type(8)));
typedef float f32x4  __attribute__((ext_vector_type(4)));

#define ASG __attribute__((address_space(1)))
#define ASL __attribute__((address_space(3)))

__device__ __forceinline__ void gl_lds16(const void* g, void* l) {
  // async global->LDS, 16B per lane; LDS dest is wave-uniform base + lane*16
  __builtin_amdgcn_global_load_lds((ASG void*)(uintptr_t)g, (ASL void*)l, 16, 0, 0);
}

__device__ __forceinline__ unsigned short f2bf(float x) {
  union { float f; unsigned u; } v; v.f = x;
  unsigned r = v.u + 0x7FFFu + ((v.u >> 16) & 1u);  // RNE
  return (unsigned short)(r >> 16);
}

// ---------------------------------------------------------------------------
// K0: conversions. Xbf (8192x2048 bf16), Wbf (1024x2048 bf16, row 1023 = 0),
// bias[1024] (W_inner col 0), Wlbf (1024x1024 bf16, rows >=1000 zero).
// Also zeros the penalty slot.
// ---------------------------------------------------------------------------
__global__ __launch_bounds__(256) void convert_kernel(
    const float* __restrict__ X, const float* __restrict__ Wi,
    const float* __restrict__ Wl, unsigned short* __restrict__ Xbf,
    unsigned short* __restrict__ Wbf, unsigned short* __restrict__ Wlbf,
    float* __restrict__ bias, float* __restrict__ pen)
{
  const int tid = blockIdx.x * 256 + threadIdx.x;
  const int stride = gridDim.x * 256;

  const float4* X4 = (const float4*)X;
  ushort4* Xb4 = (ushort4*)Xbf;
  for (int i = tid; i < (8192 * 2048) / 4; i += stride) {
    float4 v = X4[i];
    ushort4 o;
    o.x = f2bf(v.x); o.y = f2bf(v.y); o.z = f2bf(v.z); o.w = f2bf(v.w);
    Xb4[i] = o;
  }
  for (int i = tid; i < 1024 * 2048; i += stride) {
    int t = i >> 11, k = i & 2047;
    Wbf[i] = (t < 1023) ? f2bf(Wi[t * 2049 + 1 + k]) : (unsigned short)0;
  }
  for (int i = tid; i < 1024 * 1024; i += stride) {
    Wlbf[i] = (i < 1000 * 1024) ? f2bf(Wl[i]) : (unsigned short)0;
  }
  if (tid < 1024) bias[tid] = (tid < 1023) ? Wi[tid * 2049] : 0.0f;
  if (tid == 0) *pen = 0.0f;
}

// ---------------------------------------------------------------------------
// bf16 NT GEMM: C[m][n] = sum_k A[m][k]*B[n][k].
// 128x128 tile, BK=32, 4 waves of 4x4 16x16x32 MFMA.
// Deep pipeline: 3 LDS buffers, stage tile i+2 while computing tile i,
// counted vmcnt(4) (next tile's 4 loads done, tile-after-next in flight)
// + raw s_barrier. vmcnt(0) only in the epilogue. K multiple of 32, >= 96.
// Invariants per wave: each tile = 4 gl_lds issues; outstanding after stage
// = 8; vmcnt(4) completes exactly the oldest tile; barrier makes that
// machine-wide before any ds_read of its buffer.
// EPI=1: C = sigmoid(acc + bias[m]), unconditional store (GEMM1 -> p_t).
// EPI=0: plain store masked to n < nmax (GEMM2 -> logits).
// ---------------------------------------------------------------------------
#define GEMM_COMPUTE(PA, PB)                                              \
  {                                                                       \
    bf16x8 af[4], bfv[4];                                                 \
    _Pragma("unroll")                                                     \
    for (int i = 0; i < 4; ++i)                                           \
      af[i] = *(const bf16x8*)&PA[(wm + i * 16 + lr) * 32 + lk];          \
    _Pragma("unroll")                                                     \
    for (int i = 0; i < 4; ++i)                                           \
      bfv[i] = *(const bf16x8*)&PB[(wn + i * 16 + lr) * 32 + lk];         \
    _Pragma("unroll")                                                     \
    for (int mi = 0; mi < 4; ++mi)                                        \
      _Pragma("unroll")                                                   \
      for (int ni = 0; ni < 4; ++ni)                                      \
        acc[mi][ni] = __builtin_amdgcn_mfma_f32_16x16x32_bf16(            \
            af[mi], bfv[ni], acc[mi][ni], 0, 0, 0);                       \
  }

#define GEMM_STAGE(KS, PA, PB)                                            \
  {                                                                       \
    gl_lds16(ga0 + (KS), (PA) + so0);                                     \
    gl_lds16(ga1 + (KS), (PA) + so1);                                     \
    gl_lds16(gb0 + (KS), (PB) + so0);                                     \
    gl_lds16(gb1 + (KS), (PB) + so1);                                     \
  }

template <int EPI>
__global__ __launch_bounds__(256) void gemm_bt(
    const unsigned short* __restrict__ A, const unsigned short* __restrict__ B,
    float* __restrict__ C, int K, int ldc, int nmax,
    const float* __restrict__ bias)
{
  __shared__ __align__(16) unsigned short sA0[128 * 32];
  __shared__ __align__(16) unsigned short sB0[128 * 32];
  __shared__ __align__(16) unsigned short sA1[128 * 32];
  __shared__ __align__(16) unsigned short sB1[128 * 32];
  __shared__ __align__(16) unsigned short sA2[128 * 32];
  __shared__ __align__(16) unsigned short sB2[128 * 32];

  const int tid  = threadIdx.x;
  const int lane = tid & 63;
  const int wv   = tid >> 6;
  const int wm   = (wv >> 1) * 64;
  const int wn   = (wv & 1) * 64;
  const int m0   = blockIdx.y * 128;
  const int n0   = blockIdx.x * 128;
  const int lr   = lane & 15;
  const int lk   = (lane >> 4) * 8;

  f32x4 acc[4][4] = {};

  const int chunk0 = wv * 64 + lane;
  const int crow   = chunk0 >> 2;         // 0..63
  const int coff   = (chunk0 & 3) * 8;    // element offset within row
  const unsigned short* ga0 = A + (size_t)(m0 + crow) * K + coff;
  const unsigned short* ga1 = A + (size_t)(m0 + crow + 64) * K + coff;
  const unsigned short* gb0 = B + (size_t)(n0 + crow) * K + coff;
  const unsigned short* gb1 = B + (size_t)(n0 + crow + 64) * K + coff;
  const int so0 = (wv * 64) * 8;          // wave-uniform LDS offsets
  const int so1 = (256 + wv * 64) * 8;

  unsigned short *pa0 = sA0, *pa1 = sA1, *pa2 = sA2;
  unsigned short *pb0 = sB0, *pb1 = sB1, *pb2 = sB2;

  // prologue: stage tiles 0 and 1; wait for tile 0 only (tile 1 in flight)
  GEMM_STAGE(0, pa0, pb0)
  GEMM_STAGE(32, pa1, pb1)
  asm volatile("s_waitcnt vmcnt(4)" ::: "memory");
  __builtin_amdgcn_s_barrier();

  // main loop: compute tile i (pa0), stage tile i+2 (pa2); tile i+1 flying.
  for (int i = 0; i < K / 32 - 2; ++i) {
    GEMM_STAGE((i + 2) * 32, pa2, pb2)
    GEMM_COMPUTE(pa0, pb0)
    asm volatile("s_waitcnt vmcnt(4)" ::: "memory");  // tile i+1 complete
    __builtin_amdgcn_s_barrier();                     // ... machine-wide
    unsigned short* t;
    t = pa0; pa0 = pa1; pa1 = pa2; pa2 = t;
    t = pb0; pb0 = pb1; pb1 = pb2; pb2 = t;
  }

  // epilogue: tiles T-2 (pa0, complete) and T-1 (pa1, drain first)
  GEMM_COMPUTE(pa0, pb0)
  asm volatile("s_waitcnt vmcnt(0)" ::: "memory");
  __builtin_amdgcn_s_barrier();
  GEMM_COMPUTE(pa1, pb1)

  // epilogue: D[m][n], m = (lane>>4)*4 + r, n = lane&15
#pragma unroll
  for (int mi = 0; mi < 4; ++mi) {
#pragma unroll
    for (int ni = 0; ni < 4; ++ni) {
      const int mbase = m0 + wm + mi * 16 + (lane >> 4) * 4;
      const int n = n0 + wn + ni * 16 + lr;
#pragma unroll
      for (int r = 0; r < 4; ++r) {
        const int m = mbase + r;
        float v = acc[mi][ni][r];
        if (EPI == 1) {
          v += bias[m];
          v = 1.0f / (1.0f + __expf(-v));
          C[(size_t)m * ldc + n] = v;
        } else {
          if (n < nmax) C[(size_t)m * ldc + n] = v;
        }
      }
    }
  }
}

// ---------------------------------------------------------------------------
// Tree expansion over INNER nodes only (levels 0..9), transposed layout
// app_t[node][batch], heap-ordered. Pure mul+store walk — no reductions.
// Merged: blocks with subtree==0 also walk the top 31 nodes (levels 0..4).
// ---------------------------------------------------------------------------
template <int LVL, int MAXLVL>
__device__ __forceinline__ void walk(unsigned t, float mu,
                                     const float* __restrict__ p_t,
                                     float* __restrict__ app, unsigned b)
{
  app[t * 8192u + b] = mu;
  if constexpr (LVL < MAXLVL) {
    float p = p_t[t * 8192u + b];
    walk<LVL + 1, MAXLVL>(2u * t + 1u, mu * (1.0f - p), p_t, app, b);
    walk<LVL + 1, MAXLVL>(2u * t + 2u, mu * p, p_t, app, b);
  }
}

__global__ __launch_bounds__(256) void tree_expand(const float* __restrict__ p_t,
                                                   float* __restrict__ app)
{
  unsigned b = (blockIdx.x & 31u) * 256u + threadIdx.x;  // 0..8191
  unsigned s = blockIdx.x >> 5;                          // subtree 0..31
  if (s == 0) walk<0, 4>(0u, 1.0f, p_t, app, b);         // nodes 0..30
  unsigned t0 = 31u + s;                                 // level-5 root
  // recompute root mu from the 5 ancestors (rows are L2-resident)
  float mu = 1.0f;
  unsigned a = t0;
#pragma unroll
  for (int l = 0; l < 5; ++l) {
    unsigned par = (a - 1u) >> 1;
    float p = p_t[par * 8192u + b];
    mu *= (a & 1u) ? (1.0f - p) : p;   // odd = left child = (1-p)
    a = par;
  }
  walk<5, 9>(t0, mu, p_t, app, b);     // nodes 31..1022
}

// ---------------------------------------------------------------------------
// Transpose app_t (inner nodes) -> all_pp (8192x2047); leaves (t>=1023)
// recomputed from parent mu/p and additionally written to mu (8192x1024)
// and mu_bf (bf16, GEMM2 A operand).  (R2-proven 32x32 version.)
// ---------------------------------------------------------------------------
__global__ __launch_bounds__(256) void transpose_out(
    const float* __restrict__ app_t, const float* __restrict__ p_t,
    float* __restrict__ all_pp, float* __restrict__ mu_out,
    unsigned short* __restrict__ mu_bf)
{
  __shared__ float tile[32][33];
  const int b0 = blockIdx.x * 32;
  const int t0 = blockIdx.y * 32;
  const int tx = threadIdx.x;  // 0..31
  const int ty = threadIdx.y;  // 0..7

#pragma unroll
  for (int r = 0; r < 4; ++r) {
    int t = t0 + ty + r * 8;
    float v = 0.0f;
    if (t < 1023) {
      v = app_t[(size_t)t * 8192 + b0 + tx];
    } else if (t < 2047) {
      int u = (t - 1) >> 1;                       // parent (511..1022)
      float m = app_t[(size_t)u * 8192 + b0 + tx];
      float p = p_t[(size_t)u * 8192 + b0 + tx];
      v = (t & 1) ? m * (1.0f - p) : m * p;
    }
    tile[ty + r * 8][tx] = v;
  }
  __syncthreads();
#pragma unroll
  for (int r = 0; r < 4; ++r) {
    int b = b0 + ty + r * 8;
    int t = t0 + tx;
    if (t < 2047) {
      float v = tile[tx][ty + r * 8];
      all_pp[(size_t)b * 2047 + t] = v;
      if (t >= 1023) {
        int l = t - 1023;
        mu_out[(size_t)b * 1024 + l] = v;
        mu_bf[(size_t)b * 1024 + l] = f2bf(v);
      }
    }
  }
}

// ---------------------------------------------------------------------------
// Penalty: per inner node t, alpha = sum_b(p*mu)/sum_b(mu);
// pen_t = log(a)+log(1-a) (non-finite -> 0); penalty -= 0.5*2^-lvl * pen_t.
// Coalesced streaming over t-major rows (L3-warm); one atomic per block.
// ---------------------------------------------------------------------------
__global__ __launch_bounds__(256) void penalty_nodes(
    const float* __restrict__ app_t, const float* __restrict__ p_t,
    float* __restrict__ pen)
{
  const int t = blockIdx.x;  // 0..1022
  const float* mu = app_t + (size_t)t * 8192;
  const float* pp = p_t + (size_t)t * 8192;
  float num = 0.0f, den = 0.0f;
  for (int b = threadIdx.x; b < 8192; b += 256) {
    float m = mu[b];
    num += m * pp[b];
    den += m;
  }
#pragma unroll
  for (int o = 32; o; o >>= 1) {
    num += __shfl_down(num, o);
    den += __shfl_down(den, o);
  }
  __shared__ float sn[4], sd[4];
  if ((threadIdx.x & 63) == 0) {
    sn[threadIdx.x >> 6] = num;
    sd[threadIdx.x >> 6] = den;
  }
  __syncthreads();
  if (threadIdx.x == 0) {
    num = sn[0] + sn[1] + sn[2] + sn[3];
    den = sd[0] + sd[1] + sd[2] + sd[3];
    float a = num / den;
    float lg = __logf(a) + __logf(1.0f - a);
    if (!(lg > -1e30f && lg < 1e30f)) lg = 0.0f;  // NaN / +-inf -> 0
    int lvl = 31 - __clz(t + 1);
    float contrib = -0.5f * (1.0f / (float)(1 << lvl)) * lg;
    atomicAdd(pen, contrib);
  }
}

// ---------------------------------------------------------------------------
extern "C" void kernel_launch(void* const* d_in, const int* in_sizes, int n_in,
                              void* d_out, int out_size, void* d_ws,
                              size_t ws_size, hipStream_t stream)
{
  const float* X  = (const float*)d_in[0];  // 8192x2048
  const float* Wi = (const float*)d_in[1];  // 1023x2049
  const float* Wl = (const float*)d_in[2];  // 1000x1024
  float* out = (float*)d_out;

  char* ws = (char*)d_ws;
  // workspace layout (bytes):
  float* p_t            = (float*)(ws + 0);                  // 32 MB
  unsigned short* Xbf   = (unsigned short*)(ws + 33554432);  // 32 MB
  float* app_t          = (float*)(ws + 33554432);           // overlay, 32 MB
  unsigned short* mu_bf = (unsigned short*)(ws + 67108864);  // 16 MB
  unsigned short* Wbf   = (unsigned short*)(ws + 83886080);  // 4 MB
  unsigned short* Wlbf  = (unsigned short*)(ws + 88080384);  // 2 MB
  float* bias           = (float*)(ws + 90177536);           // 4 KB

  float* logits = out;                 // 8192*1000
  float* mu_out = out + 8192000;       // 8192*1024
  float* pen    = out + 16580608;      // 1
  float* all_pp = out + 16580609;      // 8192*2047

  convert_kernel<<<1024, 256, 0, stream>>>(X, Wi, Wl, Xbf, Wbf, Wlbf, bias, pen);
  // GEMM1: M=nodes(1024), N=batch(8192), K=2048 -> p_t[t][b] = sigmoid(.+bias)
  gemm_bt<1><<<dim3(64, 8), 256, 0, stream>>>(Wbf, Xbf, p_t, 2048, 8192, 8192, bias);
  tree_expand<<<1024, 256, 0, stream>>>(p_t, app_t);
  transpose_out<<<dim3(256, 64), dim3(32, 8), 0, stream>>>(app_t, p_t, all_pp, mu_out, mu_bf);
  // GEMM2: M=batch(8192), N=leafout(1024, mask 1000), K=1024 -> logits
  gemm_bt<0><<<dim3(8, 64), 256, 0, stream>>>(mu_bf, Wlbf, logits, 1024, 1000, 1000, nullptr);
  penalty_nodes<<<1023, 256, 0, stream>>>(app_t, p_t, pen);
}

// Round 7
// 363.108 us; speedup vs baseline: 1.0202x; 1.0202x over previous
//
#include <hip/hip_runtime.h>
#include <stdint.h>

// ---------------------------------------------------------------------------
// Soft Decision Tree forward: DEPTH=10, INPUT_DIM=2048, OUTPUT_DIM=1000,
// NUM_INNER=1023, NUM_LEAF=1024, BATCH=8192.
// Outputs (flat concat): logits[8192*1000], mu[8192*1024], penalty[1],
// all_pp[8192*2047].
//
// R9 = R7 (best, 354 us) with ONE change: GEMM tile 128x128 -> 256x128,
// 512 threads / 8 waves, same proven 2-phase dbuf schedule (R8's counted
// vmcnt/3-buffer pipeline regressed +16 and is reverted). 25% less staging
// per MFMA; grid = 256 blocks = 1 block/CU x 8 waves (same waves/CU).
// Pipeline: convert -> GEMM1(sigmoid) -> tree_expand -> transpose (R2) ->
// GEMM2 -> penalty_nodes.
// ---------------------------------------------------------------------------

typedef short bf16x8 __attribute__((ext_vector_type(8)));
typedef float f32x4  __attribute__((ext_vector_type(4)));

#define ASG __attribute__((address_space(1)))
#define ASL __attribute__((address_space(3)))

__device__ __forceinline__ void gl_lds16(const void* g, void* l) {
  // async global->LDS, 16B per lane; LDS dest is wave-uniform base + lane*16
  __builtin_amdgcn_global_load_lds((ASG void*)(uintptr_t)g, (ASL void*)l, 16, 0, 0);
}

__device__ __forceinline__ unsigned short f2bf(float x) {
  union { float f; unsigned u; } v; v.f = x;
  unsigned r = v.u + 0x7FFFu + ((v.u >> 16) & 1u);  // RNE
  return (unsigned short)(r >> 16);
}

// ---------------------------------------------------------------------------
// K0: conversions. Xbf (8192x2048 bf16), Wbf (1024x2048 bf16, row 1023 = 0),
// bias[1024] (W_inner col 0), Wlbf (1024x1024 bf16, rows >=1000 zero).
// Also zeros the penalty slot.
// ---------------------------------------------------------------------------
__global__ __launch_bounds__(256) void convert_kernel(
    const float* __restrict__ X, const float* __restrict__ Wi,
    const float* __restrict__ Wl, unsigned short* __restrict__ Xbf,
    unsigned short* __restrict__ Wbf, unsigned short* __restrict__ Wlbf,
    float* __restrict__ bias, float* __restrict__ pen)
{
  const int tid = blockIdx.x * 256 + threadIdx.x;
  const int stride = gridDim.x * 256;

  const float4* X4 = (const float4*)X;
  ushort4* Xb4 = (ushort4*)Xbf;
  for (int i = tid; i < (8192 * 2048) / 4; i += stride) {
    float4 v = X4[i];
    ushort4 o;
    o.x = f2bf(v.x); o.y = f2bf(v.y); o.z = f2bf(v.z); o.w = f2bf(v.w);
    Xb4[i] = o;
  }
  for (int i = tid; i < 1024 * 2048; i += stride) {
    int t = i >> 11, k = i & 2047;
    Wbf[i] = (t < 1023) ? f2bf(Wi[t * 2049 + 1 + k]) : (unsigned short)0;
  }
  for (int i = tid; i < 1024 * 1024; i += stride) {
    Wlbf[i] = (i < 1000 * 1024) ? f2bf(Wl[i]) : (unsigned short)0;
  }
  if (tid < 1024) bias[tid] = (tid < 1023) ? Wi[tid * 2049] : 0.0f;
  if (tid == 0) *pen = 0.0f;
}

// ---------------------------------------------------------------------------
// bf16 NT GEMM: C[m][n] = sum_k A[m][k]*B[n][k].
// 256x128 tile, BK=32, 8 waves (4m x 2n) of 4x4 16x16x32 MFMA, 512 threads.
// R7-proven 2-phase dbuf schedule: per K-subtile {stage next -> other buf,
// ds_read+MFMA current buf, __syncthreads}. K multiple of 64.
// M must be a multiple of 256, N of 128.
// Staging per tile: A = 1024 16B-chunks (2 issues/thread), B = 512 (1 issue).
// EPI=1: C = sigmoid(acc + bias[m]), unconditional store (GEMM1 -> p_t).
// EPI=0: plain store masked to n < nmax (GEMM2 -> logits).
// ---------------------------------------------------------------------------
#define GEMM_COMPUTE(PA, PB)                                              \
  {                                                                       \
    bf16x8 af[4], bfv[4];                                                 \
    _Pragma("unroll")                                                     \
    for (int i = 0; i < 4; ++i)                                           \
      af[i] = *(const bf16x8*)&PA[(wm + i * 16 + lr) * 32 + lk];          \
    _Pragma("unroll")                                                     \
    for (int i = 0; i < 4; ++i)                                           \
      bfv[i] = *(const bf16x8*)&PB[(wn + i * 16 + lr) * 32 + lk];         \
    _Pragma("unroll")                                                     \
    for (int mi = 0; mi < 4; ++mi)                                        \
      _Pragma("unroll")                                                   \
      for (int ni = 0; ni < 4; ++ni)                                      \
        acc[mi][ni] = __builtin_amdgcn_mfma_f32_16x16x32_bf16(            \
            af[mi], bfv[ni], acc[mi][ni], 0, 0, 0);                       \
  }

#define GEMM_STAGE(KS, PA, PB)                                            \
  {                                                                       \
    gl_lds16(ga0 + (KS), (PA) + so0);                                     \
    gl_lds16(ga1 + (KS), (PA) + so1);                                     \
    gl_lds16(gb0 + (KS), (PB) + so0);                                     \
  }

template <int EPI>
__global__ __launch_bounds__(512) void gemm_bt(
    const unsigned short* __restrict__ A, const unsigned short* __restrict__ B,
    float* __restrict__ C, int K, int ldc, int nmax,
    const float* __restrict__ bias)
{
  __shared__ __align__(16) unsigned short sA0[256 * 32];  // 16 KB
  __shared__ __align__(16) unsigned short sB0[128 * 32];  //  8 KB
  __shared__ __align__(16) unsigned short sA1[256 * 32];
  __shared__ __align__(16) unsigned short sB1[128 * 32];

  const int tid  = threadIdx.x;          // 0..511
  const int lane = tid & 63;
  const int wv   = tid >> 6;             // 0..7
  const int wm   = (wv >> 1) * 64;       // 0,64,128,192
  const int wn   = (wv & 1) * 64;        // 0,64
  const int m0   = blockIdx.y * 256;
  const int n0   = blockIdx.x * 128;
  const int lr   = lane & 15;
  const int lk   = (lane >> 4) * 8;

  f32x4 acc[4][4] = {};

  // staging geometry: chunk = 16B; row (BK=32 shorts) = 4 chunks.
  // A tile: 1024 chunks -> chunks tid (rows 0..127) and tid+512 (rows 128..255)
  // B tile: 512 chunks  -> chunk tid (rows 0..127)
  const int crow = tid >> 2;             // 0..127
  const int coff = (tid & 3) * 8;        // element offset within row
  const unsigned short* ga0 = A + (size_t)(m0 + crow) * K + coff;
  const unsigned short* ga1 = A + (size_t)(m0 + 128 + crow) * K + coff;
  const unsigned short* gb0 = B + (size_t)(n0 + crow) * K + coff;
  const int so0 = wv * 512;              // wave-uniform LDS offset (shorts)
  const int so1 = 4096 + wv * 512;       // A second half (chunk 512+)

  // prologue: stage k=0 into buf0
  GEMM_STAGE(0, sA0, sB0)
  __syncthreads();  // buf0 ready (auto vmcnt(0)+lgkmcnt(0) drain)

  for (int k0 = 0; k0 < K; k0 += 64) {
    // phase A: prefetch k0+32 -> buf1 (always exists: k0 <= K-64); compute buf0
    GEMM_STAGE(k0 + 32, sA1, sB1)
    GEMM_COMPUTE(sA0, sB0)
    __syncthreads();  // buf1 ready; all reads of buf0 drained
    // phase B: prefetch k0+64 -> buf0 (unless last); compute buf1
    if (k0 + 64 < K) {
      GEMM_STAGE(k0 + 64, sA0, sB0)
    }
    GEMM_COMPUTE(sA1, sB1)
    __syncthreads();  // buf0 ready; all reads of buf1 drained
  }

  // epilogue: D[m][n], m = (lane>>4)*4 + r, n = lane&15
#pragma unroll
  for (int mi = 0; mi < 4; ++mi) {
#pragma unroll
    for (int ni = 0; ni < 4; ++ni) {
      const int mbase = m0 + wm + mi * 16 + (lane >> 4) * 4;
      const int n = n0 + wn + ni * 16 + lr;
#pragma unroll
      for (int r = 0; r < 4; ++r) {
        const int m = mbase + r;
        float v = acc[mi][ni][r];
        if (EPI == 1) {
          v += bias[m];
          v = 1.0f / (1.0f + __expf(-v));
          C[(size_t)m * ldc + n] = v;
        } else {
          if (n < nmax) C[(size_t)m * ldc + n] = v;
        }
      }
    }
  }
}

// ---------------------------------------------------------------------------
// Tree expansion over INNER nodes only (levels 0..9), transposed layout
// app_t[node][batch], heap-ordered. Pure mul+store walk — no reductions.
// Merged: blocks with subtree==0 also walk the top 31 nodes (levels 0..4).
// ---------------------------------------------------------------------------
template <int LVL, int MAXLVL>
__device__ __forceinline__ void walk(unsigned t, float mu,
                                     const float* __restrict__ p_t,
                                     float* __restrict__ app, unsigned b)
{
  app[t * 8192u + b] = mu;
  if constexpr (LVL < MAXLVL) {
    float p = p_t[t * 8192u + b];
    walk<LVL + 1, MAXLVL>(2u * t + 1u, mu * (1.0f - p), p_t, app, b);
    walk<LVL + 1, MAXLVL>(2u * t + 2u, mu * p, p_t, app, b);
  }
}

__global__ __launch_bounds__(256) void tree_expand(const float* __restrict__ p_t,
                                                   float* __restrict__ app)
{
  unsigned b = (blockIdx.x & 31u) * 256u + threadIdx.x;  // 0..8191
  unsigned s = blockIdx.x >> 5;                          // subtree 0..31
  if (s == 0) walk<0, 4>(0u, 1.0f, p_t, app, b);         // nodes 0..30
  unsigned t0 = 31u + s;                                 // level-5 root
  // recompute root mu from the 5 ancestors (rows are L2-resident)
  float mu = 1.0f;
  unsigned a = t0;
#pragma unroll
  for (int l = 0; l < 5; ++l) {
    unsigned par = (a - 1u) >> 1;
    float p = p_t[par * 8192u + b];
    mu *= (a & 1u) ? (1.0f - p) : p;   // odd = left child = (1-p)
    a = par;
  }
  walk<5, 9>(t0, mu, p_t, app, b);     // nodes 31..1022
}

// ---------------------------------------------------------------------------
// Transpose app_t (inner nodes) -> all_pp (8192x2047); leaves (t>=1023)
// recomputed from parent mu/p and additionally written to mu (8192x1024)
// and mu_bf (bf16, GEMM2 A operand).  (R2-proven 32x32 version.)
// ---------------------------------------------------------------------------
__global__ __launch_bounds__(256) void transpose_out(
    const float* __restrict__ app_t, const float* __restrict__ p_t,
    float* __restrict__ all_pp, float* __restrict__ mu_out,
    unsigned short* __restrict__ mu_bf)
{
  __shared__ float tile[32][33];
  const int b0 = blockIdx.x * 32;
  const int t0 = blockIdx.y * 32;
  const int tx = threadIdx.x;  // 0..31
  const int ty = threadIdx.y;  // 0..7

#pragma unroll
  for (int r = 0; r < 4; ++r) {
    int t = t0 + ty + r * 8;
    float v = 0.0f;
    if (t < 1023) {
      v = app_t[(size_t)t * 8192 + b0 + tx];
    } else if (t < 2047) {
      int u = (t - 1) >> 1;                       // parent (511..1022)
      float m = app_t[(size_t)u * 8192 + b0 + tx];
      float p = p_t[(size_t)u * 8192 + b0 + tx];
      v = (t & 1) ? m * (1.0f - p) : m * p;
    }
    tile[ty + r * 8][tx] = v;
  }
  __syncthreads();
#pragma unroll
  for (int r = 0; r < 4; ++r) {
    int b = b0 + ty + r * 8;
    int t = t0 + tx;
    if (t < 2047) {
      float v = tile[tx][ty + r * 8];
      all_pp[(size_t)b * 2047 + t] = v;
      if (t >= 1023) {
        int l = t - 1023;
        mu_out[(size_t)b * 1024 + l] = v;
        mu_bf[(size_t)b * 1024 + l] = f2bf(v);
      }
    }
  }
}

// ---------------------------------------------------------------------------
// Penalty: per inner node t, alpha = sum_b(p*mu)/sum_b(mu);
// pen_t = log(a)+log(1-a) (non-finite -> 0); penalty -= 0.5*2^-lvl * pen_t.
// Coalesced streaming over t-major rows (L3-warm); one atomic per block.
// ---------------------------------------------------------------------------
__global__ __launch_bounds__(256) void penalty_nodes(
    const float* __restrict__ app_t, const float* __restrict__ p_t,
    float* __restrict__ pen)
{
  const int t = blockIdx.x;  // 0..1022
  const float* mu = app_t + (size_t)t * 8192;
  const float* pp = p_t + (size_t)t * 8192;
  float num = 0.0f, den = 0.0f;
  for (int b = threadIdx.x; b < 8192; b += 256) {
    float m = mu[b];
    num += m * pp[b];
    den += m;
  }
#pragma unroll
  for (int o = 32; o; o >>= 1) {
    num += __shfl_down(num, o);
    den += __shfl_down(den, o);
  }
  __shared__ float sn[4], sd[4];
  if ((threadIdx.x & 63) == 0) {
    sn[threadIdx.x >> 6] = num;
    sd[threadIdx.x >> 6] = den;
  }
  __syncthreads();
  if (threadIdx.x == 0) {
    num = sn[0] + sn[1] + sn[2] + sn[3];
    den = sd[0] + sd[1] + sd[2] + sd[3];
    float a = num / den;
    float lg = __logf(a) + __logf(1.0f - a);
    if (!(lg > -1e30f && lg < 1e30f)) lg = 0.0f;  // NaN / +-inf -> 0
    int lvl = 31 - __clz(t + 1);
    float contrib = -0.5f * (1.0f / (float)(1 << lvl)) * lg;
    atomicAdd(pen, contrib);
  }
}

// ---------------------------------------------------------------------------
extern "C" void kernel_launch(void* const* d_in, const int* in_sizes, int n_in,
                              void* d_out, int out_size, void* d_ws,
                              size_t ws_size, hipStream_t stream)
{
  const float* X  = (const float*)d_in[0];  // 8192x2048
  const float* Wi = (const float*)d_in[1];  // 1023x2049
  const float* Wl = (const float*)d_in[2];  // 1000x1024
  float* out = (float*)d_out;

  char* ws = (char*)d_ws;
  // workspace layout (bytes):
  float* p_t            = (float*)(ws + 0);                  // 32 MB
  unsigned short* Xbf   = (unsigned short*)(ws + 33554432);  // 32 MB
  float* app_t          = (float*)(ws + 33554432);           // overlay, 32 MB
  unsigned short* mu_bf = (unsigned short*)(ws + 67108864);  // 16 MB
  unsigned short* Wbf   = (unsigned short*)(ws + 83886080);  // 4 MB
  unsigned short* Wlbf  = (unsigned short*)(ws + 88080384);  // 2 MB
  float* bias           = (float*)(ws + 90177536);           // 4 KB

  float* logits = out;                 // 8192*1000
  float* mu_out = out + 8192000;       // 8192*1024
  float* pen    = out + 16580608;      // 1
  float* all_pp = out + 16580609;      // 8192*2047

  convert_kernel<<<1024, 256, 0, stream>>>(X, Wi, Wl, Xbf, Wbf, Wlbf, bias, pen);
  // GEMM1: M=nodes(1024), N=batch(8192), K=2048 -> p_t[t][b] = sigmoid(.+bias)
  gemm_bt<1><<<dim3(64, 4), 512, 0, stream>>>(Wbf, Xbf, p_t, 2048, 8192, 8192, bias);
  tree_expand<<<1024, 256, 0, stream>>>(p_t, app_t);
  transpose_out<<<dim3(256, 64), dim3(32, 8), 0, stream>>>(app_t, p_t, all_pp, mu_out, mu_bf);
  // GEMM2: M=batch(8192), N=leafout(1024, mask 1000), K=1024 -> logits
  gemm_bt<0><<<dim3(8, 32), 512, 0, stream>>>(mu_bf, Wlbf, logits, 1024, 1000, 1000, nullptr);
  penalty_nodes<<<1023, 256, 0, stream>>>(app_t, p_t, pen);
}

// Round 9
// 347.662 us; speedup vs baseline: 1.0655x; 1.0444x over previous
//
#include <hip/hip_runtime.h>
#include <stdint.h>

// ---------------------------------------------------------------------------
// Soft Decision Tree forward: DEPTH=10, INPUT_DIM=2048, OUTPUT_DIM=1000,
// NUM_INNER=1023, NUM_LEAF=1024, BATCH=8192.
// Outputs (flat concat): logits[8192*1000], mu[8192*1024], penalty[1],
// all_pp[8192*2047].
//
// R11 = R10 (transpose_out fused into tree_expand) with the recursive
// template walk rewritten ITERATIVELY (level-by-level, static register
// arrays) — R10 died twice on container infra; precedent (R5/R6 fail ->
// R7 rewrite ran) says restructure the unusual codegen surface.
// tree_expand produces ALL b-major outputs (all_pp, mu_out, mu_bf) straight
// from the walk via a [63][257] LDS transpose tile; transpose_out deleted.
// GEMMs/convert/penalty = R7-proven verbatim (354 us baseline).
// Pipeline: convert -> GEMM1(sigmoid) -> tree_expand(fused) -> GEMM2 ->
// penalty_nodes.
// ---------------------------------------------------------------------------

typedef short bf16x8 __attribute__((ext_vector_type(8)));
typedef float f32x4  __attribute__((ext_vector_type(4)));

#define ASG __attribute__((address_space(1)))
#define ASL __attribute__((address_space(3)))

__device__ __forceinline__ void gl_lds16(const void* g, void* l) {
  // async global->LDS, 16B per lane; LDS dest is wave-uniform base + lane*16
  __builtin_amdgcn_global_load_lds((ASG void*)(uintptr_t)g, (ASL void*)l, 16, 0, 0);
}

__device__ __forceinline__ unsigned short f2bf(float x) {
  union { float f; unsigned u; } v; v.f = x;
  unsigned r = v.u + 0x7FFFu + ((v.u >> 16) & 1u);  // RNE
  return (unsigned short)(r >> 16);
}

// ---------------------------------------------------------------------------
// K0: conversions. Xbf (8192x2048 bf16), Wbf (1024x2048 bf16, row 1023 = 0),
// bias[1024] (W_inner col 0), Wlbf (1024x1024 bf16, rows >=1000 zero).
// Also zeros the penalty slot.
// ---------------------------------------------------------------------------
__global__ __launch_bounds__(256) void convert_kernel(
    const float* __restrict__ X, const float* __restrict__ Wi,
    const float* __restrict__ Wl, unsigned short* __restrict__ Xbf,
    unsigned short* __restrict__ Wbf, unsigned short* __restrict__ Wlbf,
    float* __restrict__ bias, float* __restrict__ pen)
{
  const int tid = blockIdx.x * 256 + threadIdx.x;
  const int stride = gridDim.x * 256;

  const float4* X4 = (const float4*)X;
  ushort4* Xb4 = (ushort4*)Xbf;
  for (int i = tid; i < (8192 * 2048) / 4; i += stride) {
    float4 v = X4[i];
    ushort4 o;
    o.x = f2bf(v.x); o.y = f2bf(v.y); o.z = f2bf(v.z); o.w = f2bf(v.w);
    Xb4[i] = o;
  }
  for (int i = tid; i < 1024 * 2048; i += stride) {
    int t = i >> 11, k = i & 2047;
    Wbf[i] = (t < 1023) ? f2bf(Wi[t * 2049 + 1 + k]) : (unsigned short)0;
  }
  for (int i = tid; i < 1024 * 1024; i += stride) {
    Wlbf[i] = (i < 1000 * 1024) ? f2bf(Wl[i]) : (unsigned short)0;
  }
  if (tid < 1024) bias[tid] = (tid < 1023) ? Wi[tid * 2049] : 0.0f;
  if (tid == 0) *pen = 0.0f;
}

// ---------------------------------------------------------------------------
// bf16 NT GEMM: C[m][n] = sum_k A[m][k]*B[n][k].
// 128x128 tile, BK=32, 4 waves of 4x4 16x16x32 MFMA.  (R7-proven dbuf.)
// Double-buffered LDS; per K-subtile: {stage next -> other buf, ds_read+MFMA
// current buf, __syncthreads}. K must be a multiple of 64.
// EPI=1: C = sigmoid(acc + bias[m]), unconditional store (GEMM1 -> p_t).
// EPI=0: plain store masked to n < nmax (GEMM2 -> logits).
// ---------------------------------------------------------------------------
#define GEMM_COMPUTE(PA, PB)                                              \
  {                                                                       \
    bf16x8 af[4], bfv[4];                                                 \
    _Pragma("unroll")                                                     \
    for (int i = 0; i < 4; ++i)                                           \
      af[i] = *(const bf16x8*)&PA[(wm + i * 16 + lr) * 32 + lk];          \
    _Pragma("unroll")                                                     \
    for (int i = 0; i < 4; ++i)                                           \
      bfv[i] = *(const bf16x8*)&PB[(wn + i * 16 + lr) * 32 + lk];         \
    _Pragma("unroll")                                                     \
    for (int mi = 0; mi < 4; ++mi)                                        \
      _Pragma("unroll")                                                   \
      for (int ni = 0; ni < 4; ++ni)                                      \
        acc[mi][ni] = __builtin_amdgcn_mfma_f32_16x16x32_bf16(            \
            af[mi], bfv[ni], acc[mi][ni], 0, 0, 0);                       \
  }

template <int EPI>
__global__ __launch_bounds__(256) void gemm_bt(
    const unsigned short* __restrict__ A, const unsigned short* __restrict__ B,
    float* __restrict__ C, int K, int ldc, int nmax,
    const float* __restrict__ bias)
{
  __shared__ __align__(16) unsigned short sA0[128 * 32];
  __shared__ __align__(16) unsigned short sB0[128 * 32];
  __shared__ __align__(16) unsigned short sA1[128 * 32];
  __shared__ __align__(16) unsigned short sB1[128 * 32];

  const int tid  = threadIdx.x;
  const int lane = tid & 63;
  const int wv   = tid >> 6;
  const int wm   = (wv >> 1) * 64;
  const int wn   = (wv & 1) * 64;
  const int m0   = blockIdx.y * 128;
  const int n0   = blockIdx.x * 128;
  const int lr   = lane & 15;
  const int lk   = (lane >> 4) * 8;

  f32x4 acc[4][4] = {};

  const int chunk0 = wv * 64 + lane;
  const int crow   = chunk0 >> 2;         // 0..63
  const int coff   = (chunk0 & 3) * 8;    // element offset within row
  const unsigned short* ga0 = A + (size_t)(m0 + crow) * K + coff;
  const unsigned short* ga1 = A + (size_t)(m0 + crow + 64) * K + coff;
  const unsigned short* gb0 = B + (size_t)(n0 + crow) * K + coff;
  const unsigned short* gb1 = B + (size_t)(n0 + crow + 64) * K + coff;
  const int so0 = (wv * 64) * 8;          // wave-uniform LDS offsets
  const int so1 = (256 + wv * 64) * 8;

  // prologue: stage k=0 into buf0
  gl_lds16(ga0, sA0 + so0);
  gl_lds16(ga1, sA0 + so1);
  gl_lds16(gb0, sB0 + so0);
  gl_lds16(gb1, sB0 + so1);
  __syncthreads();  // buf0 ready (auto vmcnt(0)+lgkmcnt(0) drain)

  for (int k0 = 0; k0 < K; k0 += 64) {
    // phase A: prefetch k0+32 -> buf1 (always exists: k0 <= K-64); compute buf0
    gl_lds16(ga0 + k0 + 32, sA1 + so0);
    gl_lds16(ga1 + k0 + 32, sA1 + so1);
    gl_lds16(gb0 + k0 + 32, sB1 + so0);
    gl_lds16(gb1 + k0 + 32, sB1 + so1);
    GEMM_COMPUTE(sA0, sB0)
    __syncthreads();  // buf1 ready; all reads of buf0 drained
    // phase B: prefetch k0+64 -> buf0 (unless last); compute buf1
    if (k0 + 64 < K) {
      gl_lds16(ga0 + k0 + 64, sA0 + so0);
      gl_lds16(ga1 + k0 + 64, sA0 + so1);
      gl_lds16(gb0 + k0 + 64, sB0 + so0);
      gl_lds16(gb1 + k0 + 64, sB0 + so1);
    }
    GEMM_COMPUTE(sA1, sB1)
    __syncthreads();  // buf0 ready; all reads of buf1 drained
  }

  // epilogue: D[m][n], m = (lane>>4)*4 + r, n = lane&15
#pragma unroll
  for (int mi = 0; mi < 4; ++mi) {
#pragma unroll
    for (int ni = 0; ni < 4; ++ni) {
      const int mbase = m0 + wm + mi * 16 + (lane >> 4) * 4;
      const int n = n0 + wn + ni * 16 + lr;
#pragma unroll
      for (int r = 0; r < 4; ++r) {
        const int m = mbase + r;
        float v = acc[mi][ni][r];
        if (EPI == 1) {
          v += bias[m];
          v = 1.0f / (1.0f + __expf(-v));
          C[(size_t)m * ldc + n] = v;
        } else {
          if (n < nmax) C[(size_t)m * ldc + n] = v;
        }
      }
    }
  }
}

// ---------------------------------------------------------------------------
// Tree expansion + fused b-major outputs (ITERATIVE walk, no recursion).
// Block = (subtree s = blockIdx>>5, b-chunk = blockIdx&31, 256 b's).
// Level-by-level walk over static register arrays cur[16]/nxt[16] (all
// indices compile-time after unroll): writes app_t[t][b] (t-major, for
// penalty) and stages mu into LDS sm[row][tb] (row = local heap 0..30
// inner, 31..62 leaves computed in-walk). Store phase: wave-per-b-row reads
// LDS columns (stride 257, 2-way banks = free) and writes all_pp / mu_out /
// mu_bf with contiguous lane segments (leaves = 128B runs).
// s==0 blocks additionally walk/store the top 31 nodes (t = 0..30).
// ---------------------------------------------------------------------------
__global__ __launch_bounds__(256) void tree_expand(
    const float* __restrict__ p_t, float* __restrict__ app,
    float* __restrict__ all_pp, float* __restrict__ mu_out,
    unsigned short* __restrict__ mu_bf)
{
  __shared__ float sm[63 * 257];           // 63.2 KB; 2 blocks/CU
  const int tb   = threadIdx.x;            // 0..255
  const int lane = tb & 63;
  const int w    = tb >> 6;                // wave 0..3
  const unsigned b0 = (blockIdx.x & 31u) * 256u;
  const unsigned b  = b0 + tb;
  const int s = (int)(blockIdx.x >> 5);    // subtree 0..31

  // recompute subtree-root mu from the 5 ancestors (rows are L2-resident)
  float mu = 1.0f;
  {
    unsigned a = 31u + (unsigned)s;
#pragma unroll
    for (int l = 0; l < 5; ++l) {
      unsigned par = (a - 1u) >> 1;
      float p = p_t[par * 8192u + b];
      mu *= (a & 1u) ? (1.0f - p) : p;     // odd = left child = (1-p)
      a = par;
    }
  }

  // ---- walk levels 5..8 (local 0..3): cur -> nxt
  float cur[16] = {}, nxt[16] = {};
  cur[0] = mu;
#pragma unroll
  for (int l = 0; l < 4; ++l) {
    const int n  = 1 << l;                 // nodes this level
    const int gb = (32 << l) - 1 + (s << l);   // global heap base (level 5+l)
    const int jb = (1 << l) - 1;           // local LDS row base
#pragma unroll
    for (int i = 0; i < n; ++i) {
      const float m = cur[i];
      app[(size_t)(gb + i) * 8192 + b] = m;
      sm[(jb + i) * 257 + tb] = m;
      const float p = p_t[(size_t)(gb + i) * 8192 + b];
      nxt[2 * i]     = m * (1.0f - p);     // child 2t+1
      nxt[2 * i + 1] = m * p;              // child 2t+2
    }
#pragma unroll
    for (int i = 0; i < 16; ++i) cur[i] = nxt[i];
  }
  // ---- level 9 (local 4, 16 nodes) + the 32 leaves
  {
    const int gb = 511 + (s << 4);         // (32<<4)-1 + 16s
#pragma unroll
    for (int i = 0; i < 16; ++i) {
      const float m = cur[i];
      app[(size_t)(gb + i) * 8192 + b] = m;
      sm[(15 + i) * 257 + tb] = m;
      const float p = p_t[(size_t)(gb + i) * 8192 + b];
      sm[(31 + 2 * i) * 257 + tb] = m * (1.0f - p);
      sm[(32 + 2 * i) * 257 + tb] = m * p;
    }
  }
  __syncthreads();

  // ---- store phase: per-lane output column (constant across rows)
  int T = 0, lidx = -1;
  if (lane < 31) {
    const int lvl = 31 - __clz(lane + 1);      // local level 0..4
    const int pos = (lane + 1) - (1 << lvl);
    T = ((32 << lvl) - 1) + (s << lvl) + pos;  // global heap index
  } else if (lane < 63) {
    lidx = s * 32 + (lane - 31);               // leaf 0..1023
    T = 1023 + lidx;
  }

#pragma unroll 4
  for (int it = 0; it < 64; ++it) {
    const int bl = w + it * 4;                 // 0..255, wave-uniform
    const unsigned bb = b0 + bl;
    if (lane < 63) {
      const float v = sm[lane * 257 + bl];     // stride 257: conflict-free
      all_pp[(size_t)bb * 2047 + T] = v;
      if (lidx >= 0) {
        mu_out[(size_t)bb * 1024 + lidx] = v;
        mu_bf[(size_t)bb * 1024 + lidx]  = f2bf(v);
      }
    }
  }

  // ---- top 31 nodes, done by the 32 s==0 blocks (block-uniform branch)
  if (s == 0) {
    __syncthreads();                           // protect sm reuse
#pragma unroll
    for (int i = 0; i < 16; ++i) { cur[i] = 0.0f; nxt[i] = 0.0f; }
    cur[0] = 1.0f;
#pragma unroll
    for (int l = 0; l < 5; ++l) {
      const int n  = 1 << l;
      const int gb = (1 << l) - 1;             // global == local row here
#pragma unroll
      for (int i = 0; i < n; ++i) {
        const float m = cur[i];
        app[(size_t)(gb + i) * 8192 + b] = m;
        sm[(gb + i) * 257 + tb] = m;
        if (l < 4) {
          const float p = p_t[(size_t)(gb + i) * 8192 + b];
          nxt[2 * i]     = m * (1.0f - p);
          nxt[2 * i + 1] = m * p;
        }
      }
#pragma unroll
      for (int i = 0; i < 16; ++i) cur[i] = nxt[i];
    }
    __syncthreads();
#pragma unroll 4
    for (int it = 0; it < 64; ++it) {
      const int bl = w + it * 4;
      if (lane < 31) {
        const float v = sm[lane * 257 + bl];
        all_pp[(size_t)(b0 + bl) * 2047 + lane] = v;
      }
    }
  }
}

// ---------------------------------------------------------------------------
// Penalty: per inner node t, alpha = sum_b(p*mu)/sum_b(mu);
// pen_t = log(a)+log(1-a) (non-finite -> 0); penalty -= 0.5*2^-lvl * pen_t.
// Coalesced streaming over t-major rows (L3-warm); one atomic per block.
// ---------------------------------------------------------------------------
__global__ __launch_bounds__(256) void penalty_nodes(
    const float* __restrict__ app_t, const float* __restrict__ p_t,
    float* __restrict__ pen)
{
  const int t = blockIdx.x;  // 0..1022
  const float* mu = app_t + (size_t)t * 8192;
  const float* pp = p_t + (size_t)t * 8192;
  float num = 0.0f, den = 0.0f;
  for (int b = threadIdx.x; b < 8192; b += 256) {
    float m = mu[b];
    num += m * pp[b];
    den += m;
  }
#pragma unroll
  for (int o = 32; o; o >>= 1) {
    num += __shfl_down(num, o);
    den += __shfl_down(den, o);
  }
  __shared__ float sn[4], sd[4];
  if ((threadIdx.x & 63) == 0) {
    sn[threadIdx.x >> 6] = num;
    sd[threadIdx.x >> 6] = den;
  }
  __syncthreads();
  if (threadIdx.x == 0) {
    num = sn[0] + sn[1] + sn[2] + sn[3];
    den = sd[0] + sd[1] + sd[2] + sd[3];
    float a = num / den;
    float lg = __logf(a) + __logf(1.0f - a);
    if (!(lg > -1e30f && lg < 1e30f)) lg = 0.0f;  // NaN / +-inf -> 0
    int lvl = 31 - __clz(t + 1);
    float contrib = -0.5f * (1.0f / (float)(1 << lvl)) * lg;
    atomicAdd(pen, contrib);
  }
}

// ---------------------------------------------------------------------------
extern "C" void kernel_launch(void* const* d_in, const int* in_sizes, int n_in,
                              void* d_out, int out_size, void* d_ws,
                              size_t ws_size, hipStream_t stream)
{
  const float* X  = (const float*)d_in[0];  // 8192x2048
  const float* Wi = (const float*)d_in[1];  // 1023x2049
  const float* Wl = (const float*)d_in[2];  // 1000x1024
  float* out = (float*)d_out;

  char* ws = (char*)d_ws;
  // workspace layout (bytes):
  float* p_t            = (float*)(ws + 0);                  // 32 MB
  unsigned short* Xbf   = (unsigned short*)(ws + 33554432);  // 32 MB
  float* app_t          = (float*)(ws + 33554432);           // overlay, 32 MB
  unsigned short* mu_bf = (unsigned short*)(ws + 67108864);  // 16 MB
  unsigned short* Wbf   = (unsigned short*)(ws + 83886080);  // 4 MB
  unsigned short* Wlbf  = (unsigned short*)(ws + 88080384);  // 2 MB
  float* bias           = (float*)(ws + 90177536);           // 4 KB

  float* logits = out;                 // 8192*1000
  float* mu_out = out + 8192000;       // 8192*1024
  float* pen    = out + 16580608;      // 1
  float* all_pp = out + 16580609;      // 8192*2047

  convert_kernel<<<1024, 256, 0, stream>>>(X, Wi, Wl, Xbf, Wbf, Wlbf, bias, pen);
  // GEMM1: M=nodes(1024), N=batch(8192), K=2048 -> p_t[t][b] = sigmoid(.+bias)
  gemm_bt<1><<<dim3(64, 8), 256, 0, stream>>>(Wbf, Xbf, p_t, 2048, 8192, 8192, bias);
  // tree + fused b-major outputs (replaces tree_expand + transpose_out)
  tree_expand<<<1024, 256, 0, stream>>>(p_t, app_t, all_pp, mu_out, mu_bf);
  // GEMM2: M=batch(8192), N=leafout(1024, mask 1000), K=1024 -> logits
  gemm_bt<0><<<dim3(8, 64), 256, 0, stream>>>(mu_bf, Wlbf, logits, 1024, 1000, 1000, nullptr);
  penalty_nodes<<<1023, 256, 0, stream>>>(app_t, p_t, pen);
}

// Round 10
// 330.635 us; speedup vs baseline: 1.1204x; 1.0515x over previous
//
#include <hip/hip_runtime.h>
#include <stdint.h>

// ---------------------------------------------------------------------------
// Soft Decision Tree forward: DEPTH=10, INPUT_DIM=2048, OUTPUT_DIM=1000,
// NUM_INNER=1023, NUM_LEAF=1024, BATCH=8192.
// Outputs (flat concat): logits[8192*1000], mu[8192*1024], penalty[1],
// all_pp[8192*2047].
//
// R12 = R11 (347.7 us best) + penalty folded into tree_expand via the
// child-sum identity: num[t] = sum_b p*mu = sum_b mu[2t+2] — every node's
// mu row is already in the LDS tile, so per-block row-sums + 65K lightly-
// contended atomics replace penalty_nodes' 67 MB re-read. app_t (33.5 MB
// of writes) had no remaining consumer and is DELETED. penalty_final is a
// 1-block finisher: alpha[t] = S[2t+2]/S[t].
// GEMMs/convert = R7-proven verbatim.
// Pipeline: convert -> GEMM1(sigmoid) -> tree_expand(fused outputs+sums)
// -> GEMM2 -> penalty_final.
// ---------------------------------------------------------------------------

typedef short bf16x8 __attribute__((ext_vector_type(8)));
typedef float f32x4  __attribute__((ext_vector_type(4)));

#define ASG __attribute__((address_space(1)))
#define ASL __attribute__((address_space(3)))

__device__ __forceinline__ void gl_lds16(const void* g, void* l) {
  // async global->LDS, 16B per lane; LDS dest is wave-uniform base + lane*16
  __builtin_amdgcn_global_load_lds((ASG void*)(uintptr_t)g, (ASL void*)l, 16, 0, 0);
}

__device__ __forceinline__ unsigned short f2bf(float x) {
  union { float f; unsigned u; } v; v.f = x;
  unsigned r = v.u + 0x7FFFu + ((v.u >> 16) & 1u);  // RNE
  return (unsigned short)(r >> 16);
}

// ---------------------------------------------------------------------------
// K0: conversions. Xbf (8192x2048 bf16), Wbf (1024x2048 bf16, row 1023 = 0),
// bias[1024] (W_inner col 0), Wlbf (1024x1024 bf16, rows >=1000 zero).
// Also zeros the penalty slot and the nodesum accumulators.
// ---------------------------------------------------------------------------
__global__ __launch_bounds__(256) void convert_kernel(
    const float* __restrict__ X, const float* __restrict__ Wi,
    const float* __restrict__ Wl, unsigned short* __restrict__ Xbf,
    unsigned short* __restrict__ Wbf, unsigned short* __restrict__ Wlbf,
    float* __restrict__ bias, float* __restrict__ pen,
    float* __restrict__ nodesum)
{
  const int tid = blockIdx.x * 256 + threadIdx.x;
  const int stride = gridDim.x * 256;

  const float4* X4 = (const float4*)X;
  ushort4* Xb4 = (ushort4*)Xbf;
  for (int i = tid; i < (8192 * 2048) / 4; i += stride) {
    float4 v = X4[i];
    ushort4 o;
    o.x = f2bf(v.x); o.y = f2bf(v.y); o.z = f2bf(v.z); o.w = f2bf(v.w);
    Xb4[i] = o;
  }
  for (int i = tid; i < 1024 * 2048; i += stride) {
    int t = i >> 11, k = i & 2047;
    Wbf[i] = (t < 1023) ? f2bf(Wi[t * 2049 + 1 + k]) : (unsigned short)0;
  }
  for (int i = tid; i < 1024 * 1024; i += stride) {
    Wlbf[i] = (i < 1000 * 1024) ? f2bf(Wl[i]) : (unsigned short)0;
  }
  if (tid < 1024) bias[tid] = (tid < 1023) ? Wi[tid * 2049] : 0.0f;
  if (tid < 2047) nodesum[tid] = 0.0f;
  if (tid == 0) *pen = 0.0f;
}

// ---------------------------------------------------------------------------
// bf16 NT GEMM: C[m][n] = sum_k A[m][k]*B[n][k].
// 128x128 tile, BK=32, 4 waves of 4x4 16x16x32 MFMA.  (R7-proven dbuf.)
// Double-buffered LDS; per K-subtile: {stage next -> other buf, ds_read+MFMA
// current buf, __syncthreads}. K must be a multiple of 64.
// EPI=1: C = sigmoid(acc + bias[m]), unconditional store (GEMM1 -> p_t).
// EPI=0: plain store masked to n < nmax (GEMM2 -> logits).
// ---------------------------------------------------------------------------
#define GEMM_COMPUTE(PA, PB)                                              \
  {                                                                       \
    bf16x8 af[4], bfv[4];                                                 \
    _Pragma("unroll")                                                     \
    for (int i = 0; i < 4; ++i)                                           \
      af[i] = *(const bf16x8*)&PA[(wm + i * 16 + lr) * 32 + lk];          \
    _Pragma("unroll")                                                     \
    for (int i = 0; i < 4; ++i)                                           \
      bfv[i] = *(const bf16x8*)&PB[(wn + i * 16 + lr) * 32 + lk];         \
    _Pragma("unroll")                                                     \
    for (int mi = 0; mi < 4; ++mi)                                        \
      _Pragma("unroll")                                                   \
      for (int ni = 0; ni < 4; ++ni)                                      \
        acc[mi][ni] = __builtin_amdgcn_mfma_f32_16x16x32_bf16(            \
            af[mi], bfv[ni], acc[mi][ni], 0, 0, 0);                       \
  }

template <int EPI>
__global__ __launch_bounds__(256) void gemm_bt(
    const unsigned short* __restrict__ A, const unsigned short* __restrict__ B,
    float* __restrict__ C, int K, int ldc, int nmax,
    const float* __restrict__ bias)
{
  __shared__ __align__(16) unsigned short sA0[128 * 32];
  __shared__ __align__(16) unsigned short sB0[128 * 32];
  __shared__ __align__(16) unsigned short sA1[128 * 32];
  __shared__ __align__(16) unsigned short sB1[128 * 32];

  const int tid  = threadIdx.x;
  const int lane = tid & 63;
  const int wv   = tid >> 6;
  const int wm   = (wv >> 1) * 64;
  const int wn   = (wv & 1) * 64;
  const int m0   = blockIdx.y * 128;
  const int n0   = blockIdx.x * 128;
  const int lr   = lane & 15;
  const int lk   = (lane >> 4) * 8;

  f32x4 acc[4][4] = {};

  const int chunk0 = wv * 64 + lane;
  const int crow   = chunk0 >> 2;         // 0..63
  const int coff   = (chunk0 & 3) * 8;    // element offset within row
  const unsigned short* ga0 = A + (size_t)(m0 + crow) * K + coff;
  const unsigned short* ga1 = A + (size_t)(m0 + crow + 64) * K + coff;
  const unsigned short* gb0 = B + (size_t)(n0 + crow) * K + coff;
  const unsigned short* gb1 = B + (size_t)(n0 + crow + 64) * K + coff;
  const int so0 = (wv * 64) * 8;          // wave-uniform LDS offsets
  const int so1 = (256 + wv * 64) * 8;

  // prologue: stage k=0 into buf0
  gl_lds16(ga0, sA0 + so0);
  gl_lds16(ga1, sA0 + so1);
  gl_lds16(gb0, sB0 + so0);
  gl_lds16(gb1, sB0 + so1);
  __syncthreads();  // buf0 ready (auto vmcnt(0)+lgkmcnt(0) drain)

  for (int k0 = 0; k0 < K; k0 += 64) {
    // phase A: prefetch k0+32 -> buf1 (always exists: k0 <= K-64); compute buf0
    gl_lds16(ga0 + k0 + 32, sA1 + so0);
    gl_lds16(ga1 + k0 + 32, sA1 + so1);
    gl_lds16(gb0 + k0 + 32, sB1 + so0);
    gl_lds16(gb1 + k0 + 32, sB1 + so1);
    GEMM_COMPUTE(sA0, sB0)
    __syncthreads();  // buf1 ready; all reads of buf0 drained
    // phase B: prefetch k0+64 -> buf0 (unless last); compute buf1
    if (k0 + 64 < K) {
      gl_lds16(ga0 + k0 + 64, sA0 + so0);
      gl_lds16(ga1 + k0 + 64, sA0 + so1);
      gl_lds16(gb0 + k0 + 64, sB0 + so0);
      gl_lds16(gb1 + k0 + 64, sB0 + so1);
    }
    GEMM_COMPUTE(sA1, sB1)
    __syncthreads();  // buf0 ready; all reads of buf1 drained
  }

  // epilogue: D[m][n], m = (lane>>4)*4 + r, n = lane&15
#pragma unroll
  for (int mi = 0; mi < 4; ++mi) {
#pragma unroll
    for (int ni = 0; ni < 4; ++ni) {
      const int mbase = m0 + wm + mi * 16 + (lane >> 4) * 4;
      const int n = n0 + wn + ni * 16 + lr;
#pragma unroll
      for (int r = 0; r < 4; ++r) {
        const int m = mbase + r;
        float v = acc[mi][ni][r];
        if (EPI == 1) {
          v += bias[m];
          v = 1.0f / (1.0f + __expf(-v));
          C[(size_t)m * ldc + n] = v;
        } else {
          if (n < nmax) C[(size_t)m * ldc + n] = v;
        }
      }
    }
  }
}

// ---------------------------------------------------------------------------
// Tree expansion + fused b-major outputs + fused node row-sums.
// Block = (subtree s = blockIdx>>5, b-chunk = blockIdx&31, 256 b's).
// Iterative level-by-level walk (static register arrays) stages mu into LDS
// sm[row][tb] (row 0..30 = local inner heap, 31..62 = leaves). Store phase:
// wave-per-b-row column reads -> all_pp / mu_out / mu_bf (contiguous lane
// segments). Reduction phase: per-row 256-wide sums -> atomicAdd nodesum[T]
// (child-sum identity supplies the penalty numerator: num[t] = S[2t+2]).
// s==0 blocks additionally walk/store/reduce the top 31 nodes (t = 0..30).
// app_t is gone — no consumer remained.
// ---------------------------------------------------------------------------
__global__ __launch_bounds__(256) void tree_expand(
    const float* __restrict__ p_t, float* __restrict__ all_pp,
    float* __restrict__ mu_out, unsigned short* __restrict__ mu_bf,
    float* __restrict__ nodesum)
{
  __shared__ float sm[63 * 257];           // 63.2 KB; 2 blocks/CU
  const int tb   = threadIdx.x;            // 0..255
  const int lane = tb & 63;
  const int w    = tb >> 6;                // wave 0..3
  const unsigned b0 = (blockIdx.x & 31u) * 256u;
  const unsigned b  = b0 + tb;
  const int s = (int)(blockIdx.x >> 5);    // subtree 0..31

  // recompute subtree-root mu from the 5 ancestors (rows are L2-resident)
  float mu = 1.0f;
  {
    unsigned a = 31u + (unsigned)s;
#pragma unroll
    for (int l = 0; l < 5; ++l) {
      unsigned par = (a - 1u) >> 1;
      float p = p_t[par * 8192u + b];
      mu *= (a & 1u) ? (1.0f - p) : p;     // odd = left child = (1-p)
      a = par;
    }
  }

  // ---- walk levels 5..8 (local 0..3): cur -> nxt
  float cur[16] = {}, nxt[16] = {};
  cur[0] = mu;
#pragma unroll
  for (int l = 0; l < 4; ++l) {
    const int n  = 1 << l;                 // nodes this level
    const int gb = (32 << l) - 1 + (s << l);   // global heap base (level 5+l)
    const int jb = (1 << l) - 1;           // local LDS row base
#pragma unroll
    for (int i = 0; i < n; ++i) {
      const float m = cur[i];
      sm[(jb + i) * 257 + tb] = m;
      const float p = p_t[(size_t)(gb + i) * 8192 + b];
      nxt[2 * i]     = m * (1.0f - p);     // child 2t+1
      nxt[2 * i + 1] = m * p;              // child 2t+2
    }
#pragma unroll
    for (int i = 0; i < 16; ++i) cur[i] = nxt[i];
  }
  // ---- level 9 (local 4, 16 nodes) + the 32 leaves
  {
    const int gb = 511 + (s << 4);         // (32<<4)-1 + 16s
#pragma unroll
    for (int i = 0; i < 16; ++i) {
      const float m = cur[i];
      sm[(15 + i) * 257 + tb] = m;
      const float p = p_t[(size_t)(gb + i) * 8192 + b];
      sm[(31 + 2 * i) * 257 + tb] = m * (1.0f - p);
      sm[(32 + 2 * i) * 257 + tb] = m * p;
    }
  }
  __syncthreads();

  // ---- store phase: per-lane output column (constant across rows)
  int T = 0, lidx = -1;
  if (lane < 31) {
    const int lvl = 31 - __clz(lane + 1);      // local level 0..4
    const int pos = (lane + 1) - (1 << lvl);
    T = ((32 << lvl) - 1) + (s << lvl) + pos;  // global heap index
  } else if (lane < 63) {
    lidx = s * 32 + (lane - 31);               // leaf 0..1023
    T = 1023 + lidx;
  }

#pragma unroll 4
  for (int it = 0; it < 64; ++it) {
    const int bl = w + it * 4;                 // 0..255, wave-uniform
    const unsigned bb = b0 + bl;
    if (lane < 63) {
      const float v = sm[lane * 257 + bl];     // stride 257: conflict-free
      all_pp[(size_t)bb * 2047 + T] = v;
      if (lidx >= 0) {
        mu_out[(size_t)bb * 1024 + lidx] = v;
        mu_bf[(size_t)bb * 1024 + lidx]  = f2bf(v);
      }
    }
  }

  // ---- reduction phase: per-row sums over the 256 b's -> nodesum
  for (int r = w; r < 63; r += 4) {            // wave-uniform row
    float v = sm[r * 257 + lane] + sm[r * 257 + 64 + lane]
            + sm[r * 257 + 128 + lane] + sm[r * 257 + 192 + lane];
#pragma unroll
    for (int o = 32; o; o >>= 1) v += __shfl_down(v, o);
    if (lane == 0) {
      int Tg;
      if (r < 31) {
        const int lvl = 31 - __clz(r + 1);
        const int pos = (r + 1) - (1 << lvl);
        Tg = ((32 << lvl) - 1) + (s << lvl) + pos;
      } else {
        Tg = 1023 + s * 32 + (r - 31);
      }
      atomicAdd(&nodesum[Tg], v);
    }
  }

  // ---- top 31 nodes, done by the 32 s==0 blocks (block-uniform branch)
  if (s == 0) {
    __syncthreads();                           // all sm reads above complete
#pragma unroll
    for (int i = 0; i < 16; ++i) { cur[i] = 0.0f; nxt[i] = 0.0f; }
    cur[0] = 1.0f;
#pragma unroll
    for (int l = 0; l < 5; ++l) {
      const int n  = 1 << l;
      const int gb = (1 << l) - 1;             // global == local row here
#pragma unroll
      for (int i = 0; i < n; ++i) {
        const float m = cur[i];
        sm[(gb + i) * 257 + tb] = m;
        if (l < 4) {
          const float p = p_t[(size_t)(gb + i) * 8192 + b];
          nxt[2 * i]     = m * (1.0f - p);
          nxt[2 * i + 1] = m * p;
        }
      }
#pragma unroll
      for (int i = 0; i < 16; ++i) cur[i] = nxt[i];
    }
    __syncthreads();
#pragma unroll 4
    for (int it = 0; it < 64; ++it) {
      const int bl = w + it * 4;
      if (lane < 31) {
        const float v = sm[lane * 257 + bl];
        all_pp[(size_t)(b0 + bl) * 2047 + lane] = v;
      }
    }
    for (int r = w; r < 31; r += 4) {
      float v = sm[r * 257 + lane] + sm[r * 257 + 64 + lane]
              + sm[r * 257 + 128 + lane] + sm[r * 257 + 192 + lane];
#pragma unroll
      for (int o = 32; o; o >>= 1) v += __shfl_down(v, o);
      if (lane == 0) atomicAdd(&nodesum[r], v);
    }
  }
}

// ---------------------------------------------------------------------------
// Penalty finalize (1 block): alpha[t] = S[2t+2]/S[t] (child-sum identity:
// sum_b p*mu = right-child row sum); pen_t = log(a)+log(1-a) (non-finite ->
// 0); penalty = -sum 0.5*2^-lvl * pen_t. Overwrites *pen.
// ---------------------------------------------------------------------------
__global__ __launch_bounds__(1024) void penalty_final(
    const float* __restrict__ ns, float* __restrict__ pen)
{
  const int t = threadIdx.x;
  float c = 0.0f;
  if (t < 1023) {
    float a = ns[2 * t + 2] / ns[t];
    float lg = __logf(a) + __logf(1.0f - a);
    if (!(lg > -1e30f && lg < 1e30f)) lg = 0.0f;  // NaN / +-inf -> 0
    int lvl = 31 - __clz(t + 1);
    c = -0.5f * (1.0f / (float)(1 << lvl)) * lg;
  }
#pragma unroll
  for (int o = 32; o; o >>= 1) c += __shfl_down(c, o);
  __shared__ float red[16];
  if ((threadIdx.x & 63) == 0) red[threadIdx.x >> 6] = c;
  __syncthreads();
  if (threadIdx.x == 0) {
    float ssum = 0.0f;
#pragma unroll
    for (int i = 0; i < 16; ++i) ssum += red[i];
    *pen = ssum;
  }
}

// ---------------------------------------------------------------------------
extern "C" void kernel_launch(void* const* d_in, const int* in_sizes, int n_in,
                              void* d_out, int out_size, void* d_ws,
                              size_t ws_size, hipStream_t stream)
{
  const float* X  = (const float*)d_in[0];  // 8192x2048
  const float* Wi = (const float*)d_in[1];  // 1023x2049
  const float* Wl = (const float*)d_in[2];  // 1000x1024
  float* out = (float*)d_out;

  char* ws = (char*)d_ws;
  // workspace layout (bytes):
  float* p_t            = (float*)(ws + 0);                  // 32 MB
  unsigned short* Xbf   = (unsigned short*)(ws + 33554432);  // 32 MB
  unsigned short* mu_bf = (unsigned short*)(ws + 67108864);  // 16 MB
  unsigned short* Wbf   = (unsigned short*)(ws + 83886080);  // 4 MB
  unsigned short* Wlbf  = (unsigned short*)(ws + 88080384);  // 2 MB
  float* bias           = (float*)(ws + 90177536);           // 4 KB
  float* nodesum        = (float*)(ws + 90181632);           // 8 KB (2047 f32)

  float* logits = out;                 // 8192*1000
  float* mu_out = out + 8192000;       // 8192*1024
  float* pen    = out + 16580608;      // 1
  float* all_pp = out + 16580609;      // 8192*2047

  convert_kernel<<<1024, 256, 0, stream>>>(X, Wi, Wl, Xbf, Wbf, Wlbf, bias,
                                           pen, nodesum);
  // GEMM1: M=nodes(1024), N=batch(8192), K=2048 -> p_t[t][b] = sigmoid(.+bias)
  gemm_bt<1><<<dim3(64, 8), 256, 0, stream>>>(Wbf, Xbf, p_t, 2048, 8192, 8192, bias);
  // tree + fused b-major outputs + node row-sums (app_t eliminated)
  tree_expand<<<1024, 256, 0, stream>>>(p_t, all_pp, mu_out, mu_bf, nodesum);
  // GEMM2: M=batch(8192), N=leafout(1024, mask 1000), K=1024 -> logits
  gemm_bt<0><<<dim3(8, 64), 256, 0, stream>>>(mu_bf, Wlbf, logits, 1024, 1000, 1000, nullptr);
  penalty_final<<<1, 1024, 0, stream>>>(nodesum, pen);
}